// Round 8
// baseline (165.277 us; speedup 1.0000x reference)
//
#include <hip/hip_runtime.h>
#include <hip/hip_cooperative_groups.h>

namespace cg = cooperative_groups;

#define NV    12288
#define CIN   128
#define COUT  128
#define DEG   9
#define NB    8
#define NROWS (NB * NV)        // 98304
#define KTOT  512              // 4 segments * 128
#define BM    192              // rows per block; 512 blocks = 2/CU exactly

typedef unsigned short bfu;
typedef __attribute__((ext_vector_type(8))) short short8;
typedef __attribute__((ext_vector_type(4))) float floatx4;
typedef __attribute__((ext_vector_type(4))) unsigned short ushort4v;

__device__ __forceinline__ float bf2f(unsigned short u) {
    union { unsigned int i; float f; } x;
    x.i = ((unsigned int)u) << 16;
    return x.f;
}
__device__ __forceinline__ unsigned short f2bf(float f) {
    union { float f; unsigned int i; } x;
    x.f = f;
    unsigned int r = x.i + 0x7FFFu + ((x.i >> 16) & 1u);   // round-nearest-even
    return (unsigned short)(r >> 16);
}
__device__ __forceinline__ void gload16(const void* g, void* l) {
    __builtin_amdgcn_global_load_lds(
        (const __attribute__((address_space(1))) unsigned int*)g,
        (__attribute__((address_space(3))) unsigned int*)l, 16, 0, 0);
}

// ---------------------------------------------------------------------------
// Fused prep:
//   blocks [0, 6144)      : x fp32 -> xb bf16, 8 elems/thread
//   blocks [6144, 6400)   : W[(c*4+s)*128+o] fp32 -> Wt[o*512+s*128+c] bf16
//   block  6400           : zero stats[0..255]
// ---------------------------------------------------------------------------
__global__ __launch_bounds__(256)
void prep_kernel(const float* __restrict__ x, bfu* __restrict__ xb,
                 const float* __restrict__ W, bfu* __restrict__ Wt,
                 float* __restrict__ stats)
{
    const int blk = blockIdx.x;
    const int t   = threadIdx.x;
    if (blk < 6144) {
        const size_t i = ((size_t)blk * 256 + t) * 8;
        const float4 a = *reinterpret_cast<const float4*>(x + i);
        const float4 b = *reinterpret_cast<const float4*>(x + i + 4);
        short8 r;
        r[0] = (short)f2bf(a.x); r[1] = (short)f2bf(a.y);
        r[2] = (short)f2bf(a.z); r[3] = (short)f2bf(a.w);
        r[4] = (short)f2bf(b.x); r[5] = (short)f2bf(b.y);
        r[6] = (short)f2bf(b.z); r[7] = (short)f2bf(b.w);
        *reinterpret_cast<short8*>(xb + i) = r;
    } else if (blk < 6400) {
        const int i = (blk - 6144) * 256 + t;      // [0, 65536)
        const int o = i >> 9;
        const int kap = i & 511;
        const int s = kap >> 7;
        const int c = kap & 127;
        Wt[i] = f2bf(W[(size_t)(c * 4 + s) * COUT + o]);
    } else {
        stats[t] = 0.f;                            // t in [0,256): sum+sumsq
    }
}

// ---------------------------------------------------------------------------
// SpMM in bf16 storage, fp32 math — XCD/batch-partitioned (round-6 proven).
// ---------------------------------------------------------------------------
__global__ __launch_bounds__(256)
void spmm_bf16(const bfu* __restrict__ src, const bfu* __restrict__ sub,
               bfu* __restrict__ outp, const int* __restrict__ cols,
               const float* __restrict__ vals)
{
    const int t  = threadIdx.x;
    const int b  = blockIdx.x & 7;
    const int vt = blockIdx.x >> 3;            // 0..767
    const int v  = vt * 16 + (t >> 4);
    const int c0 = (t & 15) * 8;

    int   ec[DEG];
    float ev[DEG];
#pragma unroll
    for (int e = 0; e < DEG; ++e) {            // 16 lanes share v -> L1 broadcast
        ec[e] = cols[v * DEG + e];
        ev[e] = vals[v * DEG + e];
    }

    float acc[8];
#pragma unroll
    for (int j = 0; j < 8; ++j) acc[j] = 0.f;

    const size_t bbase = (size_t)b * NV * CIN;
#pragma unroll
    for (int e = 0; e < DEG; ++e) {
        const short8 s = *reinterpret_cast<const short8*>(
            src + bbase + (size_t)ec[e] * CIN + c0);
#pragma unroll
        for (int j = 0; j < 8; ++j)
            acc[j] = fmaf(ev[e], bf2f((unsigned short)s[j]), acc[j]);
    }

    if (sub != nullptr) {
        const short8 s0 = *reinterpret_cast<const short8*>(
            sub + bbase + (size_t)v * CIN + c0);
#pragma unroll
        for (int j = 0; j < 8; ++j)
            acc[j] = 2.f * acc[j] - bf2f((unsigned short)s0[j]);
    }

    short8 r;
#pragma unroll
    for (int j = 0; j < 8; ++j) r[j] = (short)f2bf(acc[j]);
    *reinterpret_cast<short8*>(outp + bbase + (size_t)v * CIN + c0) = r;
}

// ---------------------------------------------------------------------------
// MFMA GEMM, 2-phase pipelined (round-7 proven), + fused BN when COOP.
// BM=192, 512 blocks = 2/CU exactly (80 KB dyn LDS) -> coop co-residency.
// COOP: keep fp32 acc across grid.sync, write normalized fp32 out directly.
// ---------------------------------------------------------------------------
template<bool COOP>
__global__ __launch_bounds__(256)
void gemm_mfma(const bfu* __restrict__ A0, const bfu* __restrict__ A1,
               const bfu* __restrict__ A2, const bfu* __restrict__ A3,
               const bfu* __restrict__ Wt, bfu* __restrict__ convT,
               float* __restrict__ gstats, const float* __restrict__ gamma,
               const float* __restrict__ beta, float* __restrict__ outp)
{
    extern __shared__ char smem[];                // 81920 B
    // A dbuf: [0,24576),[24576,49152); B dbuf: [49152,65536),[65536,81920)

    const int t    = threadIdx.x;
    const int lane = t & 63;
    const int wid  = t >> 6;
    const int wr   = wid >> 1;                    // 0..1 row-wave
    const int wc   = wid & 1;                     // 0..1 col-wave
    const int rbase = blockIdx.x * BM;
    const int ck   = t & 7;                       // 16B chunk id for staging

    floatx4 acc[6][4];
#pragma unroll
    for (int m = 0; m < 6; ++m)
#pragma unroll
        for (int n = 0; n < 4; ++n) acc[m][n] = (floatx4){0.f, 0.f, 0.f, 0.f};

    const bfu* segs[4] = {A0, A1, A2, A3};

#define STAGE(KT, BUF)                                                        \
    {                                                                         \
        const bfu* As_ = segs[(KT) >> 1];                                     \
        const int  cb_ = ((KT) & 1) * 64;                                     \
        _Pragma("unroll")                                                     \
        for (int p = 0; p < 6; ++p) {                                         \
            const int flat = p * 256 + t;                                     \
            const int rr   = flat >> 3;                                       \
            gload16(As_ + (size_t)(rbase + rr) * CIN + cb_                    \
                        + ((ck ^ (rr & 7)) << 3),                             \
                    smem + (BUF) * 24576 + flat * 16);                        \
        }                                                                     \
        _Pragma("unroll")                                                     \
        for (int p = 0; p < 4; ++p) {                                         \
            const int flat = p * 256 + t;                                     \
            const int nn   = flat >> 3;                                       \
            gload16(Wt + (size_t)nn * KTOT + (KT) * 64                        \
                       + ((ck ^ (nn & 7)) << 3),                              \
                    smem + 49152 + (BUF) * 16384 + flat * 16);                \
        }                                                                     \
    }

    STAGE(0, 0);
    asm volatile("s_waitcnt vmcnt(0)\n\ts_barrier" ::: "memory");

#pragma unroll
    for (int kt = 0; kt < 8; ++kt) {
        if (kt < 7) STAGE(kt + 1, (kt + 1) & 1);  // issue next tile, no wait

        const char* abase = smem + (kt & 1) * 24576;
        const char* bbase = smem + 49152 + (kt & 1) * 16384;
#pragma unroll
        for (int ks = 0; ks < 2; ++ks) {
            const int chunk = ((ks * 4 + (lane >> 4)) ^ (lane & 7)) * 16;
            short8 a[6], b[4];
#pragma unroll
            for (int m = 0; m < 6; ++m)
                a[m] = *reinterpret_cast<const short8*>(
                    abase + (wr * 96 + m * 16 + (lane & 15)) * 128 + chunk);
#pragma unroll
            for (int n = 0; n < 4; ++n)
                b[n] = *reinterpret_cast<const short8*>(
                    bbase + (wc * 64 + n * 16 + (lane & 15)) * 128 + chunk);
#pragma unroll
            for (int m = 0; m < 6; ++m)
#pragma unroll
                for (int n = 0; n < 4; ++n)
                    acc[m][n] = __builtin_amdgcn_mfma_f32_16x16x32_bf16(
                        a[m], b[n], acc[m][n], 0, 0, 0);
        }
        if (kt < 7)
            asm volatile("s_waitcnt vmcnt(0)\n\ts_barrier" ::: "memory");
    }
#undef STAGE

    __syncthreads();                              // done with LDS tiles
    float* sred = (float*)smem;                   // alias buffer A
    float* qred = sred + COUT;
    if (t < COUT) { sred[t] = 0.f; qred[t] = 0.f; }
    __syncthreads();

    const int batch = rbase / NV;                 // 192 | 12288 -> no straddle
    const int v0 = (rbase % NV) + wr * 96 + (lane >> 4) * 4;
    const int ob = wc * 64 + (lane & 15);

    // BN partial stats from fp32 accumulators
#pragma unroll
    for (int n = 0; n < 4; ++n) {
        const int o = ob + n * 16;
        float s = 0.f, q = 0.f;
#pragma unroll
        for (int m = 0; m < 6; ++m) {
            const floatx4 v4 = acc[m][n];
#pragma unroll
            for (int j = 0; j < 4; ++j) {
                s += v4[j];
                q = fmaf(v4[j], v4[j], q);
            }
        }
        s += __shfl_xor(s, 16); s += __shfl_xor(s, 32);
        q += __shfl_xor(q, 16); q += __shfl_xor(q, 32);
        if ((lane >> 4) == 0) {
            atomicAdd(&sred[o], s);
            atomicAdd(&qred[o], q);
        }
    }
    __syncthreads();
    if (t < COUT) {
        atomicAdd(&gstats[t], sred[t]);
        atomicAdd(&gstats[COUT + t], qred[t]);
    }

    if constexpr (COOP) {
        cg::this_grid().sync();
        const float invN = 1.0f / (float)NROWS;
#pragma unroll
        for (int n = 0; n < 4; ++n) {
            const int o = ob + n * 16;
            const float mean = gstats[o] * invN;
            const float var  = gstats[COUT + o] * invN - mean * mean;
            const float sc   = rsqrtf(var + 1e-5f) * gamma[o];
            const float sh   = beta[o] - mean * sc;
            float* obase = outp + ((size_t)batch * COUT + o) * NV + v0;
#pragma unroll
            for (int m = 0; m < 6; ++m) {
                const floatx4 v4 = acc[m][n];
                float4 r;
                r.x = fmaf(v4[0], sc, sh);
                r.y = fmaf(v4[1], sc, sh);
                r.z = fmaf(v4[2], sc, sh);
                r.w = fmaf(v4[3], sc, sh);
                *reinterpret_cast<float4*>(obase + m * 16) = r;
            }
        }
    } else {
#pragma unroll
        for (int n = 0; n < 4; ++n) {
            const int o = ob + n * 16;
            bfu* cbase = convT + ((size_t)batch * COUT + o) * NV + v0;
#pragma unroll
            for (int m = 0; m < 6; ++m) {
                const floatx4 v4 = acc[m][n];
                ushort4v r;
#pragma unroll
                for (int j = 0; j < 4; ++j) r[j] = f2bf(v4[j]);
                *reinterpret_cast<ushort4v*>(cbase + m * 16) = r;
            }
        }
    }
}

// ---------------------------------------------------------------------------
// Fallback normalize (only if cooperative launch unavailable)
// ---------------------------------------------------------------------------
__global__ __launch_bounds__(256)
void normalize_bn(const bfu* __restrict__ convT, const float* __restrict__ stats,
                  const float* __restrict__ gamma, const float* __restrict__ beta,
                  float* __restrict__ outp)
{
    const size_t i = ((size_t)blockIdx.x * 256 + threadIdx.x) * 8;
    const int ch = (int)((i / NV) & (COUT - 1));   // 8 | NV -> uniform per thread
    const float invN = 1.0f / (float)NROWS;
    const float mean = stats[ch] * invN;
    const float var  = stats[COUT + ch] * invN - mean * mean;
    const float rsig = rsqrtf(var + 1e-5f);
    const float sc   = rsig * gamma[ch];
    const float sh   = beta[ch] - mean * sc;

    const short8 s = *reinterpret_cast<const short8*>(convT + i);
    float4 r0, r1;
    r0.x = fmaf(bf2f((unsigned short)s[0]), sc, sh);
    r0.y = fmaf(bf2f((unsigned short)s[1]), sc, sh);
    r0.z = fmaf(bf2f((unsigned short)s[2]), sc, sh);
    r0.w = fmaf(bf2f((unsigned short)s[3]), sc, sh);
    r1.x = fmaf(bf2f((unsigned short)s[4]), sc, sh);
    r1.y = fmaf(bf2f((unsigned short)s[5]), sc, sh);
    r1.z = fmaf(bf2f((unsigned short)s[6]), sc, sh);
    r1.w = fmaf(bf2f((unsigned short)s[7]), sc, sh);
    *reinterpret_cast<float4*>(outp + i)     = r0;
    *reinterpret_cast<float4*>(outp + i + 4) = r1;
}

// ---------------------------------------------------------------------------
extern "C" void kernel_launch(void* const* d_in, const int* in_sizes, int n_in,
                              void* d_out, int out_size, void* d_ws, size_t ws_size,
                              hipStream_t stream)
{
    (void)in_sizes; (void)n_in; (void)out_size; (void)ws_size;

    const float* x     = (const float*)d_in[0];
    const int*   cols  = (const int*)  d_in[2];
    const float* vals  = (const float*)d_in[3];
    const float* W     = (const float*)d_in[4];
    const float* gamma = (const float*)d_in[5];
    const float* beta  = (const float*)d_in[6];
    float*       out   = (float*)d_out;

    const size_t bufE = (size_t)NB * NV * CIN;      // 12,582,912 elems

    bfu* xb    = (bfu*)d_ws;
    bfu* t1    = xb + bufE;
    bfu* t2    = t1 + bufE;
    bfu* t3    = t2 + bufE;
    bfu* convT = t3 + bufE;                         // fallback path only
    bfu* Wt    = convT + bufE;                      // 65536 bf16
    float* stats = (float*)(Wt + 65536);            // 256 floats (sum|sumsq)

    const dim3 blk(256);
    const int spmm_grid = (NV / 16) * NB;           // 6144 blocks

    prep_kernel <<<6401, blk, 0, stream>>>(x, xb, W, Wt, stats);

    spmm_bf16 <<<spmm_grid, blk, 0, stream>>>(xb, nullptr, t1, cols, vals);
    spmm_bf16 <<<spmm_grid, blk, 0, stream>>>(t1, xb,      t2, cols, vals);
    spmm_bf16 <<<spmm_grid, blk, 0, stream>>>(t2, t1,      t3, cols, vals);

    {
        const bfu *a0 = xb, *a1 = t1, *a2 = t2, *a3 = t3, *wt = Wt;
        bfu* cv = convT;
        float* st = stats;
        const float *ga = gamma, *be = beta;
        float* op = out;
        void* args[] = {(void*)&a0, (void*)&a1, (void*)&a2, (void*)&a3,
                        (void*)&wt, (void*)&cv, (void*)&st, (void*)&ga,
                        (void*)&be, (void*)&op};
        hipError_t err = hipLaunchCooperativeKernel(
            (const void*)&gemm_mfma<true>, dim3(NROWS / BM), blk, args,
            81920, stream);
        if (err != hipSuccess) {
            gemm_mfma<false><<<NROWS / BM, blk, 81920, stream>>>(
                xb, t1, t2, t3, Wt, convT, stats, gamma, beta, out);
            normalize_bn<<<NROWS * CIN / (256 * 8), blk, 0, stream>>>(
                convT, stats, gamma, beta, out);
        }
    }
}

// Round 9
// 130.753 us; speedup vs baseline: 1.2640x; 1.2640x over previous
//
#include <hip/hip_runtime.h>

#define NV    12288
#define CIN   128
#define COUT  128
#define DEG   9
#define NB    8
#define NROWS (NB * NV)        // 98304
#define KTOT  512              // 4 segments * 128
#define BM    192              // rows per block; 512 blocks = 2/CU exactly

typedef unsigned short bfu;
typedef __attribute__((ext_vector_type(8))) short short8;
typedef __attribute__((ext_vector_type(4))) float floatx4;
typedef __attribute__((ext_vector_type(4))) unsigned short ushort4v;

__device__ __forceinline__ float bf2f(unsigned short u) {
    union { unsigned int i; float f; } x;
    x.i = ((unsigned int)u) << 16;
    return x.f;
}
__device__ __forceinline__ unsigned short f2bf(float f) {
    union { float f; unsigned int i; } x;
    x.f = f;
    unsigned int r = x.i + 0x7FFFu + ((x.i >> 16) & 1u);   // round-nearest-even
    return (unsigned short)(r >> 16);
}
__device__ __forceinline__ void gload16(const void* g, void* l) {
    __builtin_amdgcn_global_load_lds(
        (const __attribute__((address_space(1))) unsigned int*)g,
        (__attribute__((address_space(3))) unsigned int*)l, 16, 0, 0);
}

// ---------------------------------------------------------------------------
// Small prep: blocks [0,256): W[(c*4+s)*128+o] -> Wt[o*512+s*128+c] bf16;
//             block 256   : zero stats[0..255]
// ---------------------------------------------------------------------------
__global__ __launch_bounds__(256)
void prep_small(const float* __restrict__ W, bfu* __restrict__ Wt,
                float* __restrict__ stats)
{
    const int blk = blockIdx.x;
    const int t   = threadIdx.x;
    if (blk < 256) {
        const int i = blk * 256 + t;               // [0, 65536)
        const int o = i >> 9;
        const int kap = i & 511;
        const int s = kap >> 7;
        const int c = kap & 127;
        Wt[i] = f2bf(W[(size_t)(c * 4 + s) * COUT + o]);
    } else {
        stats[t] = 0.f;
    }
}

// ---------------------------------------------------------------------------
// First SpMM, fused with x conversion:
//   t1[b,v,c] = sum_e vals[v,e] * x[b,cols[v,e],c]   (fp32 gathers)
//   xb[b,v,c] = bf16(x[b,v,c])                       (coalesced side-write)
// Batch->XCD partition as in spmm_bf16.
// ---------------------------------------------------------------------------
__global__ __launch_bounds__(256)
void spmm_first(const float* __restrict__ xsrc, bfu* __restrict__ xb,
                bfu* __restrict__ t1out, const int* __restrict__ cols,
                const float* __restrict__ vals)
{
    const int t  = threadIdx.x;
    const int b  = blockIdx.x & 7;
    const int vt = blockIdx.x >> 3;            // 0..767
    const int v  = vt * 16 + (t >> 4);
    const int c0 = (t & 15) * 8;

    int   ec[DEG];
    float ev[DEG];
#pragma unroll
    for (int e = 0; e < DEG; ++e) {            // 16 lanes share v -> L1 broadcast
        ec[e] = cols[v * DEG + e];
        ev[e] = vals[v * DEG + e];
    }

    float acc[8];
#pragma unroll
    for (int j = 0; j < 8; ++j) acc[j] = 0.f;

    const size_t bbase = (size_t)b * NV * CIN;
#pragma unroll
    for (int e = 0; e < DEG; ++e) {
        const float* sp = xsrc + bbase + (size_t)ec[e] * CIN + c0;
        const float4 s0 = *reinterpret_cast<const float4*>(sp);
        const float4 s1 = *reinterpret_cast<const float4*>(sp + 4);
        acc[0] = fmaf(ev[e], s0.x, acc[0]);
        acc[1] = fmaf(ev[e], s0.y, acc[1]);
        acc[2] = fmaf(ev[e], s0.z, acc[2]);
        acc[3] = fmaf(ev[e], s0.w, acc[3]);
        acc[4] = fmaf(ev[e], s1.x, acc[4]);
        acc[5] = fmaf(ev[e], s1.y, acc[5]);
        acc[6] = fmaf(ev[e], s1.z, acc[6]);
        acc[7] = fmaf(ev[e], s1.w, acc[7]);
    }

    // side task: convert own row of x to bf16 (coalesced)
    {
        const float* xp = xsrc + bbase + (size_t)v * CIN + c0;
        const float4 a0 = *reinterpret_cast<const float4*>(xp);
        const float4 a1 = *reinterpret_cast<const float4*>(xp + 4);
        short8 xr;
        xr[0] = (short)f2bf(a0.x); xr[1] = (short)f2bf(a0.y);
        xr[2] = (short)f2bf(a0.z); xr[3] = (short)f2bf(a0.w);
        xr[4] = (short)f2bf(a1.x); xr[5] = (short)f2bf(a1.y);
        xr[6] = (short)f2bf(a1.z); xr[7] = (short)f2bf(a1.w);
        *reinterpret_cast<short8*>(xb + bbase + (size_t)v * CIN + c0) = xr;
    }

    short8 r;
#pragma unroll
    for (int j = 0; j < 8; ++j) r[j] = (short)f2bf(acc[j]);
    *reinterpret_cast<short8*>(t1out + bbase + (size_t)v * CIN + c0) = r;
}

// ---------------------------------------------------------------------------
// SpMM in bf16 storage, fp32 math — XCD/batch-partitioned (round-6 proven).
//   out[b,v,c] = 2*sum_e vals[v,e]*src[b,cols[v,e],c] - sub[b,v,c]
// ---------------------------------------------------------------------------
__global__ __launch_bounds__(256)
void spmm_bf16(const bfu* __restrict__ src, const bfu* __restrict__ sub,
               bfu* __restrict__ outp, const int* __restrict__ cols,
               const float* __restrict__ vals)
{
    const int t  = threadIdx.x;
    const int b  = blockIdx.x & 7;
    const int vt = blockIdx.x >> 3;            // 0..767
    const int v  = vt * 16 + (t >> 4);
    const int c0 = (t & 15) * 8;

    int   ec[DEG];
    float ev[DEG];
#pragma unroll
    for (int e = 0; e < DEG; ++e) {
        ec[e] = cols[v * DEG + e];
        ev[e] = vals[v * DEG + e];
    }

    float acc[8];
#pragma unroll
    for (int j = 0; j < 8; ++j) acc[j] = 0.f;

    const size_t bbase = (size_t)b * NV * CIN;
#pragma unroll
    for (int e = 0; e < DEG; ++e) {
        const short8 s = *reinterpret_cast<const short8*>(
            src + bbase + (size_t)ec[e] * CIN + c0);
#pragma unroll
        for (int j = 0; j < 8; ++j)
            acc[j] = fmaf(ev[e], bf2f((unsigned short)s[j]), acc[j]);
    }

    {
        const short8 s0 = *reinterpret_cast<const short8*>(
            sub + bbase + (size_t)v * CIN + c0);
#pragma unroll
        for (int j = 0; j < 8; ++j)
            acc[j] = 2.f * acc[j] - bf2f((unsigned short)s0[j]);
    }

    short8 r;
#pragma unroll
    for (int j = 0; j < 8; ++j) r[j] = (short)f2bf(acc[j]);
    *reinterpret_cast<short8*>(outp + bbase + (size_t)v * CIN + c0) = r;
}

// ---------------------------------------------------------------------------
// MFMA GEMM, 2-phase pipelined (round-7 proven): convT[b,o,v] = sum_k A*Wt.
// BM=192 (512 blocks = 2/CU, 80 KB dyn LDS), dbuf A+B, pre-swizzled
// global_load_lds, STAGE(kt+1) before compute(kt), one vmcnt(0)+barrier per
// K-step. Fused BN sum/sumsq -> gstats atomics. Writes convT bf16.
// ---------------------------------------------------------------------------
__global__ __launch_bounds__(256)
void gemm_mfma(const bfu* __restrict__ A0, const bfu* __restrict__ A1,
               const bfu* __restrict__ A2, const bfu* __restrict__ A3,
               const bfu* __restrict__ Wt, bfu* __restrict__ convT,
               float* __restrict__ gstats)
{
    extern __shared__ char smem[];                // 81920 B
    // A dbuf: [0,24576),[24576,49152); B dbuf: [49152,65536),[65536,81920)

    const int t    = threadIdx.x;
    const int lane = t & 63;
    const int wid  = t >> 6;
    const int wr   = wid >> 1;                    // 0..1 row-wave
    const int wc   = wid & 1;                     // 0..1 col-wave
    const int rbase = blockIdx.x * BM;
    const int ck   = t & 7;                       // 16B chunk id for staging

    floatx4 acc[6][4];
#pragma unroll
    for (int m = 0; m < 6; ++m)
#pragma unroll
        for (int n = 0; n < 4; ++n) acc[m][n] = (floatx4){0.f, 0.f, 0.f, 0.f};

    const bfu* segs[4] = {A0, A1, A2, A3};

#define STAGE(KT, BUF)                                                        \
    {                                                                         \
        const bfu* As_ = segs[(KT) >> 1];                                     \
        const int  cb_ = ((KT) & 1) * 64;                                     \
        _Pragma("unroll")                                                     \
        for (int p = 0; p < 6; ++p) {                                         \
            const int flat = p * 256 + t;                                     \
            const int rr   = flat >> 3;                                       \
            gload16(As_ + (size_t)(rbase + rr) * CIN + cb_                    \
                        + ((ck ^ (rr & 7)) << 3),                             \
                    smem + (BUF) * 24576 + flat * 16);                        \
        }                                                                     \
        _Pragma("unroll")                                                     \
        for (int p = 0; p < 4; ++p) {                                         \
            const int flat = p * 256 + t;                                     \
            const int nn   = flat >> 3;                                       \
            gload16(Wt + (size_t)nn * KTOT + (KT) * 64                        \
                       + ((ck ^ (nn & 7)) << 3),                              \
                    smem + 49152 + (BUF) * 16384 + flat * 16);                \
        }                                                                     \
    }

    STAGE(0, 0);
    asm volatile("s_waitcnt vmcnt(0)\n\ts_barrier" ::: "memory");

#pragma unroll
    for (int kt = 0; kt < 8; ++kt) {
        if (kt < 7) STAGE(kt + 1, (kt + 1) & 1);  // issue next tile, no wait

        const char* abase = smem + (kt & 1) * 24576;
        const char* bbase = smem + 49152 + (kt & 1) * 16384;
#pragma unroll
        for (int ks = 0; ks < 2; ++ks) {
            const int chunk = ((ks * 4 + (lane >> 4)) ^ (lane & 7)) * 16;
            short8 a[6], b[4];
#pragma unroll
            for (int m = 0; m < 6; ++m)
                a[m] = *reinterpret_cast<const short8*>(
                    abase + (wr * 96 + m * 16 + (lane & 15)) * 128 + chunk);
#pragma unroll
            for (int n = 0; n < 4; ++n)
                b[n] = *reinterpret_cast<const short8*>(
                    bbase + (wc * 64 + n * 16 + (lane & 15)) * 128 + chunk);
#pragma unroll
            for (int m = 0; m < 6; ++m)
#pragma unroll
                for (int n = 0; n < 4; ++n)
                    acc[m][n] = __builtin_amdgcn_mfma_f32_16x16x32_bf16(
                        a[m], b[n], acc[m][n], 0, 0, 0);
        }
        if (kt < 7)
            asm volatile("s_waitcnt vmcnt(0)\n\ts_barrier" ::: "memory");
    }
#undef STAGE

    __syncthreads();                              // done with LDS tiles
    float* sred = (float*)smem;                   // alias buffer A
    float* qred = sred + COUT;
    if (t < COUT) { sred[t] = 0.f; qred[t] = 0.f; }
    __syncthreads();

    // epilogue: convT[b,o,v] bf16 + BN partial stats
    const int batch = rbase / NV;                 // 192 | 12288 -> no straddle
    const int v0 = (rbase % NV) + wr * 96 + (lane >> 4) * 4;
    const int ob = wc * 64 + (lane & 15);

#pragma unroll
    for (int n = 0; n < 4; ++n) {
        const int o = ob + n * 16;
        float s = 0.f, q = 0.f;
        bfu* cbase = convT + ((size_t)batch * COUT + o) * NV + v0;
#pragma unroll
        for (int m = 0; m < 6; ++m) {
            const floatx4 v4 = acc[m][n];
            ushort4v r;
#pragma unroll
            for (int j = 0; j < 4; ++j) {
                r[j] = f2bf(v4[j]);
                s += v4[j];
                q = fmaf(v4[j], v4[j], q);
            }
            *reinterpret_cast<ushort4v*>(cbase + m * 16) = r;
        }
        s += __shfl_xor(s, 16); s += __shfl_xor(s, 32);
        q += __shfl_xor(q, 16); q += __shfl_xor(q, 32);
        if ((lane >> 4) == 0) {
            atomicAdd(&sred[o], s);
            atomicAdd(&qred[o], q);
        }
    }
    __syncthreads();
    if (t < COUT) {
        atomicAdd(&gstats[t], sred[t]);
        atomicAdd(&gstats[COUT + t], qred[t]);
    }
}

// ---------------------------------------------------------------------------
// out[b,o,v] = (convT[b,o,v]-mean[o])*rsig[o]*gamma[o] + beta[o]
// ---------------------------------------------------------------------------
__global__ __launch_bounds__(256)
void normalize_bn(const bfu* __restrict__ convT, const float* __restrict__ stats,
                  const float* __restrict__ gamma, const float* __restrict__ beta,
                  float* __restrict__ outp)
{
    const size_t i = ((size_t)blockIdx.x * 256 + threadIdx.x) * 8;
    const int ch = (int)((i / NV) & (COUT - 1));   // 8 | NV -> uniform per thread
    const float invN = 1.0f / (float)NROWS;
    const float mean = stats[ch] * invN;
    const float var  = stats[COUT + ch] * invN - mean * mean;
    const float rsig = rsqrtf(var + 1e-5f);
    const float sc   = rsig * gamma[ch];
    const float sh   = beta[ch] - mean * sc;

    const short8 s = *reinterpret_cast<const short8*>(convT + i);
    float4 r0, r1;
    r0.x = fmaf(bf2f((unsigned short)s[0]), sc, sh);
    r0.y = fmaf(bf2f((unsigned short)s[1]), sc, sh);
    r0.z = fmaf(bf2f((unsigned short)s[2]), sc, sh);
    r0.w = fmaf(bf2f((unsigned short)s[3]), sc, sh);
    r1.x = fmaf(bf2f((unsigned short)s[4]), sc, sh);
    r1.y = fmaf(bf2f((unsigned short)s[5]), sc, sh);
    r1.z = fmaf(bf2f((unsigned short)s[6]), sc, sh);
    r1.w = fmaf(bf2f((unsigned short)s[7]), sc, sh);
    *reinterpret_cast<float4*>(outp + i)     = r0;
    *reinterpret_cast<float4*>(outp + i + 4) = r1;
}

// ---------------------------------------------------------------------------
extern "C" void kernel_launch(void* const* d_in, const int* in_sizes, int n_in,
                              void* d_out, int out_size, void* d_ws, size_t ws_size,
                              hipStream_t stream)
{
    (void)in_sizes; (void)n_in; (void)out_size; (void)ws_size;

    const float* x     = (const float*)d_in[0];
    const int*   cols  = (const int*)  d_in[2];
    const float* vals  = (const float*)d_in[3];
    const float* W     = (const float*)d_in[4];
    const float* gamma = (const float*)d_in[5];
    const float* beta  = (const float*)d_in[6];
    float*       out   = (float*)d_out;

    const size_t bufE = (size_t)NB * NV * CIN;      // 12,582,912 elems

    bfu* xb    = (bfu*)d_ws;
    bfu* t1    = xb + bufE;
    bfu* t2    = t1 + bufE;
    bfu* t3    = t2 + bufE;
    bfu* convT = t3 + bufE;
    bfu* Wt    = convT + bufE;                      // 65536 bf16
    float* stats = (float*)(Wt + 65536);            // 256 floats (sum|sumsq)

    const dim3 blk(256);
    const int spmm_grid = (NV / 16) * NB;           // 6144 blocks

    prep_small <<<257, blk, 0, stream>>>(W, Wt, stats);

    spmm_first <<<spmm_grid, blk, 0, stream>>>(x, xb, t1, cols, vals);
    spmm_bf16  <<<spmm_grid, blk, 0, stream>>>(t1, xb, t2, cols, vals);
    spmm_bf16  <<<spmm_grid, blk, 0, stream>>>(t2, t1, t3, cols, vals);

    gemm_mfma <<<NROWS / BM, blk, 81920, stream>>>(xb, t1, t2, t3, Wt, convT, stats);

    normalize_bn <<<NROWS * CIN / (256 * 8), blk, 0, stream>>>(
        convT, stats, gamma, beta, out);
}

// Round 10
// 119.909 us; speedup vs baseline: 1.3784x; 1.0904x over previous
//
#include <hip/hip_runtime.h>

#define NV    12288
#define CIN   128
#define COUT  128
#define DEG   9
#define NB    8
#define NROWS (NB * NV)        // 98304
#define KTOT  512              // 4 segments * 128
#define BM    192              // rows per block; 512 blocks = 2/CU exactly

typedef unsigned short bfu;
typedef __attribute__((ext_vector_type(8))) short short8;
typedef __attribute__((ext_vector_type(4))) float floatx4;
typedef __attribute__((ext_vector_type(4))) unsigned short ushort4v;

__device__ __forceinline__ float bf2f(unsigned short u) {
    union { unsigned int i; float f; } x;
    x.i = ((unsigned int)u) << 16;
    return x.f;
}
__device__ __forceinline__ unsigned short f2bf(float f) {
    union { float f; unsigned int i; } x;
    x.f = f;
    unsigned int r = x.i + 0x7FFFu + ((x.i >> 16) & 1u);   // round-nearest-even
    return (unsigned short)(r >> 16);
}
__device__ __forceinline__ void gload16(const void* g, void* l) {
    __builtin_amdgcn_global_load_lds(
        (const __attribute__((address_space(1))) unsigned int*)g,
        (__attribute__((address_space(3))) unsigned int*)l, 16, 0, 0);
}

// ---------------------------------------------------------------------------
// Fused prep (round-7 proven):
//   blocks [0, 6144)      : x fp32 -> xb bf16, 8 elems/thread
//   blocks [6144, 6400)   : W[(c*4+s)*128+o] fp32 -> Wt[o*512+s*128+c] bf16
//   block  6400           : zero stats[0..255]
// ---------------------------------------------------------------------------
__global__ __launch_bounds__(256)
void prep_kernel(const float* __restrict__ x, bfu* __restrict__ xb,
                 const float* __restrict__ W, bfu* __restrict__ Wt,
                 float* __restrict__ stats)
{
    const int blk = blockIdx.x;
    const int t   = threadIdx.x;
    if (blk < 6144) {
        const size_t i = ((size_t)blk * 256 + t) * 8;
        const float4 a = *reinterpret_cast<const float4*>(x + i);
        const float4 b = *reinterpret_cast<const float4*>(x + i + 4);
        short8 r;
        r[0] = (short)f2bf(a.x); r[1] = (short)f2bf(a.y);
        r[2] = (short)f2bf(a.z); r[3] = (short)f2bf(a.w);
        r[4] = (short)f2bf(b.x); r[5] = (short)f2bf(b.y);
        r[6] = (short)f2bf(b.z); r[7] = (short)f2bf(b.w);
        *reinterpret_cast<short8*>(xb + i) = r;
    } else if (blk < 6400) {
        const int i = (blk - 6144) * 256 + t;      // [0, 65536)
        const int o = i >> 9;
        const int kap = i & 511;
        const int s = kap >> 7;
        const int c = kap & 127;
        Wt[i] = f2bf(W[(size_t)(c * 4 + s) * COUT + o]);
    } else {
        stats[t] = 0.f;
    }
}

// ---------------------------------------------------------------------------
// SpMM in bf16 storage, fp32 math — XCD/batch-partitioned (round-6 proven).
// ---------------------------------------------------------------------------
__global__ __launch_bounds__(256)
void spmm_bf16(const bfu* __restrict__ src, const bfu* __restrict__ sub,
               bfu* __restrict__ outp, const int* __restrict__ cols,
               const float* __restrict__ vals)
{
    const int t  = threadIdx.x;
    const int b  = blockIdx.x & 7;
    const int vt = blockIdx.x >> 3;            // 0..767
    const int v  = vt * 16 + (t >> 4);
    const int c0 = (t & 15) * 8;

    int   ec[DEG];
    float ev[DEG];
#pragma unroll
    for (int e = 0; e < DEG; ++e) {            // 16 lanes share v -> L1 broadcast
        ec[e] = cols[v * DEG + e];
        ev[e] = vals[v * DEG + e];
    }

    float acc[8];
#pragma unroll
    for (int j = 0; j < 8; ++j) acc[j] = 0.f;

    const size_t bbase = (size_t)b * NV * CIN;
#pragma unroll
    for (int e = 0; e < DEG; ++e) {
        const short8 s = *reinterpret_cast<const short8*>(
            src + bbase + (size_t)ec[e] * CIN + c0);
#pragma unroll
        for (int j = 0; j < 8; ++j)
            acc[j] = fmaf(ev[e], bf2f((unsigned short)s[j]), acc[j]);
    }

    if (sub != nullptr) {
        const short8 s0 = *reinterpret_cast<const short8*>(
            sub + bbase + (size_t)v * CIN + c0);
#pragma unroll
        for (int j = 0; j < 8; ++j)
            acc[j] = 2.f * acc[j] - bf2f((unsigned short)s0[j]);
    }

    short8 r;
#pragma unroll
    for (int j = 0; j < 8; ++j) r[j] = (short)f2bf(acc[j]);
    *reinterpret_cast<short8*>(outp + bbase + (size_t)v * CIN + c0) = r;
}

// ---------------------------------------------------------------------------
// MFMA GEMM, 3-stage counted-vmcnt pipeline: convT[b,o,v] = sum_k A*Wt.
// BM=192, BK=32, 16 K-steps. LDS: A 3x12K @ {0,12288,24576};
// B 3x8K @ 36864+{0,8192,16384} = 60 KB -> 2 blocks/CU (grid 512 = exact).
// Stage(kt+2) issued at top of iter kt; "s_waitcnt vmcnt(5); s_barrier" at
// bottom (counted — one stage = 5 loads stays in flight; never drains to 0
// until the tail). XOR-swizzle (rr>>1)&3 on 16B chunks: 2 lanes/bank (free).
// Accumulation order over k identical to the BK=64 version (bitwise-same).
// Fused BN sum/sumsq -> gstats atomics. Writes convT bf16.
// ---------------------------------------------------------------------------
__global__ __launch_bounds__(256)
void gemm_mfma(const bfu* __restrict__ A0, const bfu* __restrict__ A1,
               const bfu* __restrict__ A2, const bfu* __restrict__ A3,
               const bfu* __restrict__ Wt, bfu* __restrict__ convT,
               float* __restrict__ gstats)
{
    extern __shared__ char smem[];                // 61440 B

    const int t    = threadIdx.x;
    const int lane = t & 63;
    const int wid  = t >> 6;
    const int wr   = wid >> 1;                    // 0..1 row-wave
    const int wc   = wid & 1;                     // 0..1 col-wave
    const int rbase = blockIdx.x * BM;

    floatx4 acc[6][4];
#pragma unroll
    for (int m = 0; m < 6; ++m)
#pragma unroll
        for (int n = 0; n < 4; ++n) acc[m][n] = (floatx4){0.f, 0.f, 0.f, 0.f};

    const bfu* segs[4] = {A0, A1, A2, A3};

    // A tile: [192 rows][32 k] bf16 (64 B/row, 4 chunks); 3 passes.
    // B tile: [128 o  ][32 k] bf16 (64 B/row, 4 chunks); 2 passes.
    // LDS slot ck holds source chunk (ck ^ ((rr>>1)&3)).
#define STAGE(KT, BUF)                                                        \
    {                                                                         \
        const bfu* As_ = segs[(KT) >> 2];                                     \
        const int  cb_ = ((KT) & 3) * 32;                                     \
        _Pragma("unroll")                                                     \
        for (int p = 0; p < 3; ++p) {                                         \
            const int flat = p * 256 + t;                                     \
            const int rr   = flat >> 2;                                       \
            const int ck   = flat & 3;                                        \
            gload16(As_ + (size_t)(rbase + rr) * CIN + cb_                    \
                        + ((ck ^ ((rr >> 1) & 3)) << 3),                      \
                    smem + (BUF) * 12288 + flat * 16);                        \
        }                                                                     \
        _Pragma("unroll")                                                     \
        for (int p = 0; p < 2; ++p) {                                         \
            const int flat = p * 256 + t;                                     \
            const int nn   = flat >> 2;                                       \
            const int ck   = flat & 3;                                        \
            gload16(Wt + (size_t)nn * KTOT + (KT) * 32                        \
                       + ((ck ^ ((nn >> 1) & 3)) << 3),                       \
                    smem + 36864 + (BUF) * 8192 + flat * 16);                 \
        }                                                                     \
    }

    STAGE(0, 0);
    STAGE(1, 1);
    asm volatile("s_waitcnt vmcnt(5)\n\ts_barrier" ::: "memory");  // tile 0 ready

    const int rsw   = ((lane & 15) >> 1) & 3;     // row-swizzle bits (m,n-invariant)
    const int chunk = ((lane >> 4) ^ rsw) * 16;   // byte offset of wanted k-chunk

#pragma unroll
    for (int kt = 0; kt < 16; ++kt) {
        if (kt + 2 < 16) STAGE(kt + 2, (kt + 2) % 3);   // 2-deep prefetch

        const char* abase = smem + (kt % 3) * 12288;
        const char* bbase = smem + 36864 + (kt % 3) * 8192;
        short8 a[6], b[4];
#pragma unroll
        for (int m = 0; m < 6; ++m)
            a[m] = *reinterpret_cast<const short8*>(
                abase + (wr * 96 + m * 16 + (lane & 15)) * 64 + chunk);
#pragma unroll
        for (int n = 0; n < 4; ++n)
            b[n] = *reinterpret_cast<const short8*>(
                bbase + (wc * 64 + n * 16 + (lane & 15)) * 64 + chunk);
#pragma unroll
        for (int m = 0; m < 6; ++m)
#pragma unroll
            for (int n = 0; n < 4; ++n)
                acc[m][n] = __builtin_amdgcn_mfma_f32_16x16x32_bf16(
                    a[m], b[n], acc[m][n], 0, 0, 0);

        // need tile kt+1 landed before next iter; allow this iter's 5 in flight
        if (kt <= 13)
            asm volatile("s_waitcnt vmcnt(5)\n\ts_barrier" ::: "memory");
        else if (kt == 14)
            asm volatile("s_waitcnt vmcnt(0)\n\ts_barrier" ::: "memory");
    }
#undef STAGE

    __syncthreads();                              // done with LDS tiles
    float* sred = (float*)smem;                   // alias buffer A0
    float* qred = sred + COUT;
    if (t < COUT) { sred[t] = 0.f; qred[t] = 0.f; }
    __syncthreads();

    // epilogue: convT[b,o,v] bf16 + BN partial stats
    const int batch = rbase / NV;                 // 192 | 12288 -> no straddle
    const int v0 = (rbase % NV) + wr * 96 + (lane >> 4) * 4;
    const int ob = wc * 64 + (lane & 15);

#pragma unroll
    for (int n = 0; n < 4; ++n) {
        const int o = ob + n * 16;
        float s = 0.f, q = 0.f;
        bfu* cbase = convT + ((size_t)batch * COUT + o) * NV + v0;
#pragma unroll
        for (int m = 0; m < 6; ++m) {
            const floatx4 v4 = acc[m][n];
            ushort4v r;
#pragma unroll
            for (int j = 0; j < 4; ++j) {
                r[j] = f2bf(v4[j]);
                s += v4[j];
                q = fmaf(v4[j], v4[j], q);
            }
            *reinterpret_cast<ushort4v*>(cbase + m * 16) = r;
        }
        s += __shfl_xor(s, 16); s += __shfl_xor(s, 32);
        q += __shfl_xor(q, 16); q += __shfl_xor(q, 32);
        if ((lane >> 4) == 0) {
            atomicAdd(&sred[o], s);
            atomicAdd(&qred[o], q);
        }
    }
    __syncthreads();
    if (t < COUT) {
        atomicAdd(&gstats[t], sred[t]);
        atomicAdd(&gstats[COUT + t], qred[t]);
    }
}

// ---------------------------------------------------------------------------
// out[b,o,v] = (convT[b,o,v]-mean[o])*rsig[o]*gamma[o] + beta[o]
// ---------------------------------------------------------------------------
__global__ __launch_bounds__(256)
void normalize_bn(const bfu* __restrict__ convT, const float* __restrict__ stats,
                  const float* __restrict__ gamma, const float* __restrict__ beta,
                  float* __restrict__ outp)
{
    const size_t i = ((size_t)blockIdx.x * 256 + threadIdx.x) * 8;
    const int ch = (int)((i / NV) & (COUT - 1));   // 8 | NV -> uniform per thread
    const float invN = 1.0f / (float)NROWS;
    const float mean = stats[ch] * invN;
    const float var  = stats[COUT + ch] * invN - mean * mean;
    const float rsig = rsqrtf(var + 1e-5f);
    const float sc   = rsig * gamma[ch];
    const float sh   = beta[ch] - mean * sc;

    const short8 s = *reinterpret_cast<const short8*>(convT + i);
    float4 r0, r1;
    r0.x = fmaf(bf2f((unsigned short)s[0]), sc, sh);
    r0.y = fmaf(bf2f((unsigned short)s[1]), sc, sh);
    r0.z = fmaf(bf2f((unsigned short)s[2]), sc, sh);
    r0.w = fmaf(bf2f((unsigned short)s[3]), sc, sh);
    r1.x = fmaf(bf2f((unsigned short)s[4]), sc, sh);
    r1.y = fmaf(bf2f((unsigned short)s[5]), sc, sh);
    r1.z = fmaf(bf2f((unsigned short)s[6]), sc, sh);
    r1.w = fmaf(bf2f((unsigned short)s[7]), sc, sh);
    *reinterpret_cast<float4*>(outp + i)     = r0;
    *reinterpret_cast<float4*>(outp + i + 4) = r1;
}

// ---------------------------------------------------------------------------
extern "C" void kernel_launch(void* const* d_in, const int* in_sizes, int n_in,
                              void* d_out, int out_size, void* d_ws, size_t ws_size,
                              hipStream_t stream)
{
    (void)in_sizes; (void)n_in; (void)out_size; (void)ws_size;

    const float* x     = (const float*)d_in[0];
    const int*   cols  = (const int*)  d_in[2];
    const float* vals  = (const float*)d_in[3];
    const float* W     = (const float*)d_in[4];
    const float* gamma = (const float*)d_in[5];
    const float* beta  = (const float*)d_in[6];
    float*       out   = (float*)d_out;

    const size_t bufE = (size_t)NB * NV * CIN;      // 12,582,912 elems

    bfu* xb    = (bfu*)d_ws;
    bfu* t1    = xb + bufE;
    bfu* t2    = t1 + bufE;
    bfu* t3    = t2 + bufE;
    bfu* convT = t3 + bufE;
    bfu* Wt    = convT + bufE;                      // 65536 bf16
    float* stats = (float*)(Wt + 65536);            // 256 floats (sum|sumsq)

    const dim3 blk(256);
    const int spmm_grid = (NV / 16) * NB;           // 6144 blocks

    prep_kernel <<<6401, blk, 0, stream>>>(x, xb, W, Wt, stats);

    spmm_bf16 <<<spmm_grid, blk, 0, stream>>>(xb, nullptr, t1, cols, vals);
    spmm_bf16 <<<spmm_grid, blk, 0, stream>>>(t1, xb,      t2, cols, vals);
    spmm_bf16 <<<spmm_grid, blk, 0, stream>>>(t2, t1,      t3, cols, vals);

    gemm_mfma <<<NROWS / BM, blk, 61440, stream>>>(xb, t1, t2, t3, Wt, convT, stats);

    normalize_bn <<<NROWS * CIN / (256 * 8), blk, 0, stream>>>(
        convT, stats, gamma, beta, out);
}

// Round 11
// 117.419 us; speedup vs baseline: 1.4076x; 1.0212x over previous
//
#include <hip/hip_runtime.h>

#define NV    12288
#define CIN   128
#define COUT  128
#define DEG   9
#define NB    8
#define NROWS (NB * NV)        // 98304
#define KTOT  512              // 4 segments * 128
#define BM    384              // rows per block; 256 blocks = 1/CU exactly

typedef unsigned short bfu;
typedef __attribute__((ext_vector_type(8))) short short8;
typedef __attribute__((ext_vector_type(4))) float floatx4;
typedef __attribute__((ext_vector_type(4))) unsigned short ushort4v;

__device__ __forceinline__ float bf2f(unsigned short u) {
    union { unsigned int i; float f; } x;
    x.i = ((unsigned int)u) << 16;
    return x.f;
}
__device__ __forceinline__ unsigned short f2bf(float f) {
    union { float f; unsigned int i; } x;
    x.f = f;
    unsigned int r = x.i + 0x7FFFu + ((x.i >> 16) & 1u);   // round-nearest-even
    return (unsigned short)(r >> 16);
}
__device__ __forceinline__ void gload16(const void* g, void* l) {
    __builtin_amdgcn_global_load_lds(
        (const __attribute__((address_space(1))) unsigned int*)g,
        (__attribute__((address_space(3))) unsigned int*)l, 16, 0, 0);
}

// ---------------------------------------------------------------------------
// Fused prep (round-7 proven):
//   blocks [0, 6144)      : x fp32 -> xb bf16, 8 elems/thread
//   blocks [6144, 6400)   : W[(c*4+s)*128+o] fp32 -> Wt[o*512+s*128+c] bf16
//   block  6400           : zero stats[0..255]
// ---------------------------------------------------------------------------
__global__ __launch_bounds__(256)
void prep_kernel(const float* __restrict__ x, bfu* __restrict__ xb,
                 const float* __restrict__ W, bfu* __restrict__ Wt,
                 float* __restrict__ stats)
{
    const int blk = blockIdx.x;
    const int t   = threadIdx.x;
    if (blk < 6144) {
        const size_t i = ((size_t)blk * 256 + t) * 8;
        const float4 a = *reinterpret_cast<const float4*>(x + i);
        const float4 b = *reinterpret_cast<const float4*>(x + i + 4);
        short8 r;
        r[0] = (short)f2bf(a.x); r[1] = (short)f2bf(a.y);
        r[2] = (short)f2bf(a.z); r[3] = (short)f2bf(a.w);
        r[4] = (short)f2bf(b.x); r[5] = (short)f2bf(b.y);
        r[6] = (short)f2bf(b.z); r[7] = (short)f2bf(b.w);
        *reinterpret_cast<short8*>(xb + i) = r;
    } else if (blk < 6400) {
        const int i = (blk - 6144) * 256 + t;      // [0, 65536)
        const int o = i >> 9;
        const int kap = i & 511;
        const int s = kap >> 7;
        const int c = kap & 127;
        Wt[i] = f2bf(W[(size_t)(c * 4 + s) * COUT + o]);
    } else {
        stats[t] = 0.f;
    }
}

// ---------------------------------------------------------------------------
// SpMM in bf16 storage, fp32 math — XCD/batch-partitioned (round-6 proven).
// ---------------------------------------------------------------------------
__global__ __launch_bounds__(256)
void spmm_bf16(const bfu* __restrict__ src, const bfu* __restrict__ sub,
               bfu* __restrict__ outp, const int* __restrict__ cols,
               const float* __restrict__ vals)
{
    const int t  = threadIdx.x;
    const int b  = blockIdx.x & 7;
    const int vt = blockIdx.x >> 3;            // 0..767
    const int v  = vt * 16 + (t >> 4);
    const int c0 = (t & 15) * 8;

    int   ec[DEG];
    float ev[DEG];
#pragma unroll
    for (int e = 0; e < DEG; ++e) {            // 16 lanes share v -> L1 broadcast
        ec[e] = cols[v * DEG + e];
        ev[e] = vals[v * DEG + e];
    }

    float acc[8];
#pragma unroll
    for (int j = 0; j < 8; ++j) acc[j] = 0.f;

    const size_t bbase = (size_t)b * NV * CIN;
#pragma unroll
    for (int e = 0; e < DEG; ++e) {
        const short8 s = *reinterpret_cast<const short8*>(
            src + bbase + (size_t)ec[e] * CIN + c0);
#pragma unroll
        for (int j = 0; j < 8; ++j)
            acc[j] = fmaf(ev[e], bf2f((unsigned short)s[j]), acc[j]);
    }

    if (sub != nullptr) {
        const short8 s0 = *reinterpret_cast<const short8*>(
            sub + bbase + (size_t)v * CIN + c0);
#pragma unroll
        for (int j = 0; j < 8; ++j)
            acc[j] = 2.f * acc[j] - bf2f((unsigned short)s0[j]);
    }

    short8 r;
#pragma unroll
    for (int j = 0; j < 8; ++j) r[j] = (short)f2bf(acc[j]);
    *reinterpret_cast<short8*>(outp + bbase + (size_t)v * CIN + c0) = r;
}

// ---------------------------------------------------------------------------
// MFMA GEMM, BM=384 / 1 block/CU, 3-stage counted-vmcnt pipeline.
// convT[b,o,v] = sum_k A[r,k]*Wt[o,k], K=512, BK=32, 16 K-steps.
// 512 thr = 8 waves (4 m x 2 n), wave tile 96x64 = 6x4 frags.
// LDS 96 KB: A 3x24K @ {0,24576,49152}; B 3x8K @ 73728+{0,8192,16384}.
// STAGE(kt+2) at top of iter kt; "s_waitcnt vmcnt(4); s_barrier" at bottom
// (one 4-load stage stays in flight; drains only at tail).
// XOR-swizzle (rr>>1)&3 on 16B chunks (round-10 proven, 2 lanes/bank).
// B re-staging halves vs BM=192: 131KB x 256 blocks = 33.5 MB.
// Fused BN sum/sumsq -> gstats atomics. Writes convT bf16.
// ---------------------------------------------------------------------------
__global__ __launch_bounds__(512)
void gemm_mfma(const bfu* __restrict__ A0, const bfu* __restrict__ A1,
               const bfu* __restrict__ A2, const bfu* __restrict__ A3,
               const bfu* __restrict__ Wt, bfu* __restrict__ convT,
               float* __restrict__ gstats)
{
    extern __shared__ char smem[];                // 98304 B

    const int t    = threadIdx.x;
    const int lane = t & 63;
    const int wid  = t >> 6;                      // 0..7
    const int wr   = wid >> 1;                    // 0..3 row-wave
    const int wc   = wid & 1;                     // 0..1 col-wave
    const int rbase = blockIdx.x * BM;

    floatx4 acc[6][4];
#pragma unroll
    for (int m = 0; m < 6; ++m)
#pragma unroll
        for (int n = 0; n < 4; ++n) acc[m][n] = (floatx4){0.f, 0.f, 0.f, 0.f};

    const bfu* segs[4] = {A0, A1, A2, A3};

    // A tile: [384 rows][32 k] bf16 (64 B/row = 4 chunks); 3 chunks/thread.
    // B tile: [128 o  ][32 k] bf16; 1 chunk/thread.
#define STAGE(KT, BUF)                                                        \
    {                                                                         \
        const bfu* As_ = segs[(KT) >> 2];                                     \
        const int  cb_ = ((KT) & 3) * 32;                                     \
        _Pragma("unroll")                                                     \
        for (int p = 0; p < 3; ++p) {                                         \
            const int flat = p * 512 + t;                                     \
            const int rr   = flat >> 2;                                       \
            const int ck   = flat & 3;                                        \
            gload16(As_ + (size_t)(rbase + rr) * CIN + cb_                    \
                        + ((ck ^ ((rr >> 1) & 3)) << 3),                      \
                    smem + (BUF) * 24576 + flat * 16);                        \
        }                                                                     \
        {                                                                     \
            const int nn = t >> 2;                                            \
            const int ck = t & 3;                                             \
            gload16(Wt + (size_t)nn * KTOT + (KT) * 32                        \
                       + ((ck ^ ((nn >> 1) & 3)) << 3),                       \
                    smem + 73728 + (BUF) * 8192 + t * 16);                    \
        }                                                                     \
    }

    STAGE(0, 0);
    STAGE(1, 1);
    asm volatile("s_waitcnt vmcnt(4)\n\ts_barrier" ::: "memory");  // tile 0 ready

    const int rsw   = ((lane & 15) >> 1) & 3;     // row-swizzle bits
    const int chunk = ((lane >> 4) ^ rsw) * 16;   // byte offset of wanted k-chunk

#pragma unroll
    for (int kt = 0; kt < 16; ++kt) {
        if (kt + 2 < 16) STAGE(kt + 2, (kt + 2) % 3);   // 2-deep prefetch

        const char* abase = smem + (kt % 3) * 24576;
        const char* bbase = smem + 73728 + (kt % 3) * 8192;
        short8 a[6], b[4];
#pragma unroll
        for (int m = 0; m < 6; ++m)
            a[m] = *reinterpret_cast<const short8*>(
                abase + (wr * 96 + m * 16 + (lane & 15)) * 64 + chunk);
#pragma unroll
        for (int n = 0; n < 4; ++n)
            b[n] = *reinterpret_cast<const short8*>(
                bbase + (wc * 64 + n * 16 + (lane & 15)) * 64 + chunk);
#pragma unroll
        for (int m = 0; m < 6; ++m)
#pragma unroll
            for (int n = 0; n < 4; ++n)
                acc[m][n] = __builtin_amdgcn_mfma_f32_16x16x32_bf16(
                    a[m], b[n], acc[m][n], 0, 0, 0);

        if (kt <= 13)
            asm volatile("s_waitcnt vmcnt(4)\n\ts_barrier" ::: "memory");
        else if (kt == 14)
            asm volatile("s_waitcnt vmcnt(0)\n\ts_barrier" ::: "memory");
    }
#undef STAGE

    __syncthreads();                              // done with LDS tiles
    float* sred = (float*)smem;                   // alias buffer A0
    float* qred = sred + COUT;
    if (t < COUT) { sred[t] = 0.f; qred[t] = 0.f; }
    __syncthreads();

    // epilogue: convT[b,o,v] bf16 + BN partial stats
    const int batch = rbase / NV;                 // 384 | 12288 -> no straddle
    const int v0 = (rbase % NV) + wr * 96 + (lane >> 4) * 4;
    const int ob = wc * 64 + (lane & 15);

#pragma unroll
    for (int n = 0; n < 4; ++n) {
        const int o = ob + n * 16;
        float s = 0.f, q = 0.f;
        bfu* cbase = convT + ((size_t)batch * COUT + o) * NV + v0;
#pragma unroll
        for (int m = 0; m < 6; ++m) {
            const floatx4 v4 = acc[m][n];
            ushort4v r;
#pragma unroll
            for (int j = 0; j < 4; ++j) {
                r[j] = f2bf(v4[j]);
                s += v4[j];
                q = fmaf(v4[j], v4[j], q);
            }
            *reinterpret_cast<ushort4v*>(cbase + m * 16) = r;
        }
        s += __shfl_xor(s, 16); s += __shfl_xor(s, 32);
        q += __shfl_xor(q, 16); q += __shfl_xor(q, 32);
        if ((lane >> 4) == 0) {
            atomicAdd(&sred[o], s);
            atomicAdd(&qred[o], q);
        }
    }
    __syncthreads();
    if (t < COUT) {
        atomicAdd(&gstats[t], sred[t]);
        atomicAdd(&gstats[COUT + t], qred[t]);
    }
}

// ---------------------------------------------------------------------------
// out[b,o,v] = (convT[b,o,v]-mean[o])*rsig[o]*gamma[o] + beta[o]
// ---------------------------------------------------------------------------
__global__ __launch_bounds__(256)
void normalize_bn(const bfu* __restrict__ convT, const float* __restrict__ stats,
                  const float* __restrict__ gamma, const float* __restrict__ beta,
                  float* __restrict__ outp)
{
    const size_t i = ((size_t)blockIdx.x * 256 + threadIdx.x) * 8;
    const int ch = (int)((i / NV) & (COUT - 1));   // 8 | NV -> uniform per thread
    const float invN = 1.0f / (float)NROWS;
    const float mean = stats[ch] * invN;
    const float var  = stats[COUT + ch] * invN - mean * mean;
    const float rsig = rsqrtf(var + 1e-5f);
    const float sc   = rsig * gamma[ch];
    const float sh   = beta[ch] - mean * sc;

    const short8 s = *reinterpret_cast<const short8*>(convT + i);
    float4 r0, r1;
    r0.x = fmaf(bf2f((unsigned short)s[0]), sc, sh);
    r0.y = fmaf(bf2f((unsigned short)s[1]), sc, sh);
    r0.z = fmaf(bf2f((unsigned short)s[2]), sc, sh);
    r0.w = fmaf(bf2f((unsigned short)s[3]), sc, sh);
    r1.x = fmaf(bf2f((unsigned short)s[4]), sc, sh);
    r1.y = fmaf(bf2f((unsigned short)s[5]), sc, sh);
    r1.z = fmaf(bf2f((unsigned short)s[6]), sc, sh);
    r1.w = fmaf(bf2f((unsigned short)s[7]), sc, sh);
    *reinterpret_cast<float4*>(outp + i)     = r0;
    *reinterpret_cast<float4*>(outp + i + 4) = r1;
}

// ---------------------------------------------------------------------------
extern "C" void kernel_launch(void* const* d_in, const int* in_sizes, int n_in,
                              void* d_out, int out_size, void* d_ws, size_t ws_size,
                              hipStream_t stream)
{
    (void)in_sizes; (void)n_in; (void)out_size; (void)ws_size;

    const float* x     = (const float*)d_in[0];
    const int*   cols  = (const int*)  d_in[2];
    const float* vals  = (const float*)d_in[3];
    const float* W     = (const float*)d_in[4];
    const float* gamma = (const float*)d_in[5];
    const float* beta  = (const float*)d_in[6];
    float*       out   = (float*)d_out;

    const size_t bufE = (size_t)NB * NV * CIN;      // 12,582,912 elems

    bfu* xb    = (bfu*)d_ws;
    bfu* t1    = xb + bufE;
    bfu* t2    = t1 + bufE;
    bfu* t3    = t2 + bufE;
    bfu* convT = t3 + bufE;
    bfu* Wt    = convT + bufE;                      // 65536 bf16
    float* stats = (float*)(Wt + 65536);            // 256 floats (sum|sumsq)

    const dim3 blk(256);
    const int spmm_grid = (NV / 16) * NB;           // 6144 blocks

    prep_kernel <<<6401, blk, 0, stream>>>(x, xb, W, Wt, stats);

    spmm_bf16 <<<spmm_grid, blk, 0, stream>>>(xb, nullptr, t1, cols, vals);
    spmm_bf16 <<<spmm_grid, blk, 0, stream>>>(t1, xb,      t2, cols, vals);
    spmm_bf16 <<<spmm_grid, blk, 0, stream>>>(t2, t1,      t3, cols, vals);

    gemm_mfma <<<NROWS / BM, dim3(512), 98304, stream>>>(
        xb, t1, t2, t3, Wt, convT, stats);

    normalize_bn <<<NROWS * CIN / (256 * 8), blk, 0, stream>>>(
        convT, stats, gamma, beta, out);
}

// Round 12
// 115.628 us; speedup vs baseline: 1.4294x; 1.0155x over previous
//
#include <hip/hip_runtime.h>

#define NV    12288
#define CIN   128
#define COUT  128
#define DEG   9
#define NB    8
#define NROWS (NB * NV)        // 98304
#define KTOT  512              // 4 segments * 128
#define BM    384              // rows per block; 256 blocks = 1/CU exactly

typedef unsigned short bfu;
typedef __attribute__((ext_vector_type(8))) short short8;
typedef __attribute__((ext_vector_type(4))) float floatx4;

__device__ __forceinline__ float bf2f(unsigned short u) {
    union { unsigned int i; float f; } x;
    x.i = ((unsigned int)u) << 16;
    return x.f;
}
__device__ __forceinline__ unsigned short f2bf(float f) {
    union { float f; unsigned int i; } x;
    x.f = f;
    unsigned int r = x.i + 0x7FFFu + ((x.i >> 16) & 1u);   // round-nearest-even
    return (unsigned short)(r >> 16);
}
__device__ __forceinline__ void gload16(const void* g, void* l) {
    __builtin_amdgcn_global_load_lds(
        (const __attribute__((address_space(1))) unsigned int*)g,
        (__attribute__((address_space(3))) unsigned int*)l, 16, 0, 0);
}

// ---------------------------------------------------------------------------
// Fused prep (round-7 proven):
//   blocks [0, 6144)      : x fp32 -> xb bf16, 8 elems/thread
//   blocks [6144, 6400)   : W[(c*4+s)*128+o] fp32 -> Wt[o*512+s*128+c] bf16
//   block  6400           : zero stats[0..255] + barrier counter stats[256]
// ---------------------------------------------------------------------------
__global__ __launch_bounds__(256)
void prep_kernel(const float* __restrict__ x, bfu* __restrict__ xb,
                 const float* __restrict__ W, bfu* __restrict__ Wt,
                 float* __restrict__ stats)
{
    const int blk = blockIdx.x;
    const int t   = threadIdx.x;
    if (blk < 6144) {
        const size_t i = ((size_t)blk * 256 + t) * 8;
        const float4 a = *reinterpret_cast<const float4*>(x + i);
        const float4 b = *reinterpret_cast<const float4*>(x + i + 4);
        short8 r;
        r[0] = (short)f2bf(a.x); r[1] = (short)f2bf(a.y);
        r[2] = (short)f2bf(a.z); r[3] = (short)f2bf(a.w);
        r[4] = (short)f2bf(b.x); r[5] = (short)f2bf(b.y);
        r[6] = (short)f2bf(b.z); r[7] = (short)f2bf(b.w);
        *reinterpret_cast<short8*>(xb + i) = r;
    } else if (blk < 6400) {
        const int i = (blk - 6144) * 256 + t;      // [0, 65536)
        const int o = i >> 9;
        const int kap = i & 511;
        const int s = kap >> 7;
        const int c = kap & 127;
        Wt[i] = f2bf(W[(size_t)(c * 4 + s) * COUT + o]);
    } else {
        stats[t] = 0.f;                            // sum | sumsq
        if (t == 0) stats[2 * COUT] = 0.f;         // spin-barrier counter
    }
}

// ---------------------------------------------------------------------------
// SpMM in bf16 storage, fp32 math — XCD/batch-partitioned (round-6 proven).
// ---------------------------------------------------------------------------
__global__ __launch_bounds__(256)
void spmm_bf16(const bfu* __restrict__ src, const bfu* __restrict__ sub,
               bfu* __restrict__ outp, const int* __restrict__ cols,
               const float* __restrict__ vals)
{
    const int t  = threadIdx.x;
    const int b  = blockIdx.x & 7;
    const int vt = blockIdx.x >> 3;            // 0..767
    const int v  = vt * 16 + (t >> 4);
    const int c0 = (t & 15) * 8;

    int   ec[DEG];
    float ev[DEG];
#pragma unroll
    for (int e = 0; e < DEG; ++e) {            // 16 lanes share v -> L1 broadcast
        ec[e] = cols[v * DEG + e];
        ev[e] = vals[v * DEG + e];
    }

    float acc[8];
#pragma unroll
    for (int j = 0; j < 8; ++j) acc[j] = 0.f;

    const size_t bbase = (size_t)b * NV * CIN;
#pragma unroll
    for (int e = 0; e < DEG; ++e) {
        const short8 s = *reinterpret_cast<const short8*>(
            src + bbase + (size_t)ec[e] * CIN + c0);
#pragma unroll
        for (int j = 0; j < 8; ++j)
            acc[j] = fmaf(ev[e], bf2f((unsigned short)s[j]), acc[j]);
    }

    if (sub != nullptr) {
        const short8 s0 = *reinterpret_cast<const short8*>(
            sub + bbase + (size_t)v * CIN + c0);
#pragma unroll
        for (int j = 0; j < 8; ++j)
            acc[j] = 2.f * acc[j] - bf2f((unsigned short)s0[j]);
    }

    short8 r;
#pragma unroll
    for (int j = 0; j < 8; ++j) r[j] = (short)f2bf(acc[j]);
    *reinterpret_cast<short8*>(outp + bbase + (size_t)v * CIN + c0) = r;
}

// ---------------------------------------------------------------------------
// MFMA GEMM + fused BN via software grid barrier.
// Round-11 proven body: BM=384, 1 block/CU (96 KB LDS), 512 thr (8 waves,
// 4m x 2n, wave tile 96x64), BK=32, 3-stage counted-vmcnt pipeline.
// Epilogue: block stats -> gstats atomics -> spin barrier (256 blocks all
// co-resident: grid == #CUs, 1 block/CU by LDS) -> normalize own acc ->
// write fp32 out[b,o,v] directly. No convT, no separate normalize pass.
// __launch_bounds__(512,2): 256-VGPR cap (rounds 4/8 failed on 128-cap spill).
// ---------------------------------------------------------------------------
__global__ __launch_bounds__(512, 2)
void gemm_mfma(const bfu* __restrict__ A0, const bfu* __restrict__ A1,
               const bfu* __restrict__ A2, const bfu* __restrict__ A3,
               const bfu* __restrict__ Wt, float* __restrict__ gstats,
               const float* __restrict__ gamma, const float* __restrict__ beta,
               float* __restrict__ outp)
{
    extern __shared__ char smem[];                // 98304 B

    const int t    = threadIdx.x;
    const int lane = t & 63;
    const int wid  = t >> 6;                      // 0..7
    const int wr   = wid >> 1;                    // 0..3 row-wave
    const int wc   = wid & 1;                     // 0..1 col-wave
    const int rbase = blockIdx.x * BM;

    floatx4 acc[6][4];
#pragma unroll
    for (int m = 0; m < 6; ++m)
#pragma unroll
        for (int n = 0; n < 4; ++n) acc[m][n] = (floatx4){0.f, 0.f, 0.f, 0.f};

    const bfu* segs[4] = {A0, A1, A2, A3};

#define STAGE(KT, BUF)                                                        \
    {                                                                         \
        const bfu* As_ = segs[(KT) >> 2];                                     \
        const int  cb_ = ((KT) & 3) * 32;                                     \
        _Pragma("unroll")                                                     \
        for (int p = 0; p < 3; ++p) {                                         \
            const int flat = p * 512 + t;                                     \
            const int rr   = flat >> 2;                                       \
            const int ck   = flat & 3;                                        \
            gload16(As_ + (size_t)(rbase + rr) * CIN + cb_                    \
                        + ((ck ^ ((rr >> 1) & 3)) << 3),                      \
                    smem + (BUF) * 24576 + flat * 16);                        \
        }                                                                     \
        {                                                                     \
            const int nn = t >> 2;                                            \
            const int ck = t & 3;                                             \
            gload16(Wt + (size_t)nn * KTOT + (KT) * 32                        \
                       + ((ck ^ ((nn >> 1) & 3)) << 3),                       \
                    smem + 73728 + (BUF) * 8192 + t * 16);                    \
        }                                                                     \
    }

    STAGE(0, 0);
    STAGE(1, 1);
    asm volatile("s_waitcnt vmcnt(4)\n\ts_barrier" ::: "memory");  // tile 0 ready

    const int rsw   = ((lane & 15) >> 1) & 3;     // row-swizzle bits
    const int chunk = ((lane >> 4) ^ rsw) * 16;   // byte offset of wanted k-chunk

#pragma unroll
    for (int kt = 0; kt < 16; ++kt) {
        if (kt + 2 < 16) STAGE(kt + 2, (kt + 2) % 3);   // 2-deep prefetch

        const char* abase = smem + (kt % 3) * 24576;
        const char* bbase = smem + 73728 + (kt % 3) * 8192;
        short8 a[6], b[4];
#pragma unroll
        for (int m = 0; m < 6; ++m)
            a[m] = *reinterpret_cast<const short8*>(
                abase + (wr * 96 + m * 16 + (lane & 15)) * 64 + chunk);
#pragma unroll
        for (int n = 0; n < 4; ++n)
            b[n] = *reinterpret_cast<const short8*>(
                bbase + (wc * 64 + n * 16 + (lane & 15)) * 64 + chunk);
#pragma unroll
        for (int m = 0; m < 6; ++m)
#pragma unroll
            for (int n = 0; n < 4; ++n)
                acc[m][n] = __builtin_amdgcn_mfma_f32_16x16x32_bf16(
                    a[m], b[n], acc[m][n], 0, 0, 0);

        if (kt <= 13)
            asm volatile("s_waitcnt vmcnt(4)\n\ts_barrier" ::: "memory");
        else if (kt == 14)
            asm volatile("s_waitcnt vmcnt(0)\n\ts_barrier" ::: "memory");
    }
#undef STAGE

    __syncthreads();                              // done with LDS tiles
    float* sred = (float*)smem;                   // alias buffer A0
    float* qred = sred + COUT;
    if (t < COUT) { sred[t] = 0.f; qred[t] = 0.f; }
    __syncthreads();

    const int batch = rbase / NV;                 // 384 | 12288 -> no straddle
    const int v0 = (rbase % NV) + wr * 96 + (lane >> 4) * 4;
    const int ob = wc * 64 + (lane & 15);

    // block-local BN partial stats -> gstats atomics
#pragma unroll
    for (int n = 0; n < 4; ++n) {
        const int o = ob + n * 16;
        float s = 0.f, q = 0.f;
#pragma unroll
        for (int m = 0; m < 6; ++m) {
            const floatx4 v4 = acc[m][n];
#pragma unroll
            for (int j = 0; j < 4; ++j) {
                s += v4[j];
                q = fmaf(v4[j], v4[j], q);
            }
        }
        s += __shfl_xor(s, 16); s += __shfl_xor(s, 32);
        q += __shfl_xor(q, 16); q += __shfl_xor(q, 32);
        if ((lane >> 4) == 0) {
            atomicAdd(&sred[o], s);
            atomicAdd(&qred[o], q);
        }
    }
    __syncthreads();
    if (t < COUT) {
        atomicAdd(&gstats[t], sred[t]);
        atomicAdd(&gstats[COUT + t], qred[t]);
    }
    __syncthreads();                              // drains the atomics (vmcnt 0)

    // ---- software grid barrier (256 blocks, all co-resident: 1/CU) ----
    unsigned int* ctr = (unsigned int*)&gstats[2 * COUT];
    if (t == 0) {
        __threadfence();                          // publish this block's atomics
        atomicAdd(ctr, 1u);
        while (__hip_atomic_load(ctr, __ATOMIC_RELAXED,
                                 __HIP_MEMORY_SCOPE_AGENT) < gridDim.x) { }
        __threadfence();                          // acquire completed gstats
    }
    __syncthreads();

    // normalize own accumulators, write fp32 out[b,o,v]
    const float invN = 1.0f / (float)NROWS;
#pragma unroll
    for (int n = 0; n < 4; ++n) {
        const int o = ob + n * 16;
        const float mean = gstats[o] * invN;
        const float var  = gstats[COUT + o] * invN - mean * mean;
        const float sc   = rsqrtf(var + 1e-5f) * gamma[o];
        const float sh   = beta[o] - mean * sc;
        float* obase = outp + ((size_t)batch * COUT + o) * NV + v0;
#pragma unroll
        for (int m = 0; m < 6; ++m) {
            const floatx4 v4 = acc[m][n];
            float4 r;
            r.x = fmaf(v4[0], sc, sh);
            r.y = fmaf(v4[1], sc, sh);
            r.z = fmaf(v4[2], sc, sh);
            r.w = fmaf(v4[3], sc, sh);
            *reinterpret_cast<float4*>(obase + m * 16) = r;
        }
    }
}

// ---------------------------------------------------------------------------
extern "C" void kernel_launch(void* const* d_in, const int* in_sizes, int n_in,
                              void* d_out, int out_size, void* d_ws, size_t ws_size,
                              hipStream_t stream)
{
    (void)in_sizes; (void)n_in; (void)out_size; (void)ws_size;

    const float* x     = (const float*)d_in[0];
    const int*   cols  = (const int*)  d_in[2];
    const float* vals  = (const float*)d_in[3];
    const float* W     = (const float*)d_in[4];
    const float* gamma = (const float*)d_in[5];
    const float* beta  = (const float*)d_in[6];
    float*       out   = (float*)d_out;

    const size_t bufE = (size_t)NB * NV * CIN;      // 12,582,912 elems

    bfu* xb    = (bfu*)d_ws;
    bfu* t1    = xb + bufE;
    bfu* t2    = t1 + bufE;
    bfu* t3    = t2 + bufE;
    bfu* Wt    = t3 + bufE;                         // 65536 bf16
    float* stats = (float*)(Wt + 65536);            // 257 floats (sum|sumsq|ctr)

    const dim3 blk(256);
    const int spmm_grid = (NV / 16) * NB;           // 6144 blocks

    prep_kernel <<<6401, blk, 0, stream>>>(x, xb, W, Wt, stats);

    spmm_bf16 <<<spmm_grid, blk, 0, stream>>>(xb, nullptr, t1, cols, vals);
    spmm_bf16 <<<spmm_grid, blk, 0, stream>>>(t1, xb,      t2, cols, vals);
    spmm_bf16 <<<spmm_grid, blk, 0, stream>>>(t2, t1,      t3, cols, vals);

    gemm_mfma <<<NROWS / BM, dim3(512), 98304, stream>>>(
        xb, t1, t2, t3, Wt, stats, gamma, beta, out);
}